// Round 10
// baseline (89.320 us; speedup 1.0000x reference)
//
#include <hip/hip_runtime.h>

#define N_USER   100000
#define N_ITEM   200000
#define N_NODES  300000
#define NNZ      4000000
#define EMB      64
#define N_LAYERS 3
#define BATCH    4096
#define NSLOT    (3*BATCH)   // 12288
#define MAXE     96          // bucket capacity; edges/node ~ Poisson(13.3)
#define SLABS    3907        // ceil(1M int4 tiles / 256)
#define SLABCAP  128         // hits per 1024-edge block ~ N(42,6.5) -> 13 sigma

// ---------------- ws layout ----------------
// [0]         u16  table16[N_NODES]       600,000 B (pad 600,064)
// [600064]    int  count[NSLOT]           49,152 B
// [649216]    int2 csr2[NSLOT*MAXE]       9,437,184 B  (col, val-bits)
// [10086400]  float side[NSLOT*EMB]       3,145,728 B
// [13232128]  int  slabcnt[4096]          16,384 B
// [13248512]  int2 hitlist[SLABS*SLABCAP] 4,000,768 B   -> ends 17,249,280

#define TBL4   37500     // 600,000/16
#define CNT4   3072      // 49,152/16
#define SCNT4  1024      // 16,384/16

__global__ void __launch_bounds__(256) k_clear(int4* __restrict__ t4,
                                               int4* __restrict__ c4,
                                               int4* __restrict__ s4) {
    int i = blockIdx.x * blockDim.x + threadIdx.x;
    if (i < TBL4)                     t4[i] = make_int4(-1, -1, -1, -1);
    else if (i < TBL4 + CNT4)         c4[i - TBL4] = make_int4(0, 0, 0, 0);
    else if (i < TBL4 + CNT4 + SCNT4) s4[i - TBL4 - CNT4] = make_int4(0, 0, 0, 0);
}

__global__ void k_setup(const int* __restrict__ users,
                        const int* __restrict__ pos,
                        const int* __restrict__ neg,
                        unsigned short* __restrict__ table16) {
    int i = blockIdx.x * blockDim.x + threadIdx.x;
    if (i >= NSLOT) return;
    int node;
    if (i < BATCH)            node = users[i];
    else if (i < 2 * BATCH)   node = N_USER + pos[i - BATCH];
    else                      node = N_USER + neg[i - 2 * BATCH];
    table16[node] = (unsigned short)i;        // benign race on duplicates (winner consistent)
}

// lean scan: row stream + table test + LDS compact -> private slab. NO global atomics.
__global__ void __launch_bounds__(256) k_scan(
        const int* __restrict__ row,
        const unsigned short* __restrict__ table16,
        const int* __restrict__ col,          // fallback only
        const float* __restrict__ vals,       // fallback only
        int* __restrict__ count,              // fallback only
        int2* __restrict__ csr2,              // fallback only
        int* __restrict__ slabcnt,
        int2* __restrict__ hitlist) {
    __shared__ int2 lh[SLABCAP];
    __shared__ int cnt;
    int tid = threadIdx.x;
    if (tid == 0) cnt = 0;
    __syncthreads();

    int t = blockIdx.x * 256 + tid;           // int4-tile index (4 edges)
    if (t < NNZ / 4) {
        int4 r = ((const int4*)row)[t];
        int ss[4];
        ss[0] = (int)(short)table16[r.x];
        ss[1] = (int)(short)table16[r.y];
        ss[2] = (int)(short)table16[r.z];
        ss[3] = (int)(short)table16[r.w];
        int e = t * 4;
        #pragma unroll
        for (int i = 0; i < 4; ++i) {
            if (ss[i] >= 0) {
                int p = atomicAdd(&cnt, 1);   // LDS atomic
                if (p < SLABCAP) lh[p] = make_int2(e + i, ss[i]);
                else {                        // statistically never (13 sigma)
                    int pp = atomicAdd(&count[ss[i]], 1);
                    if (pp < MAXE)
                        csr2[(size_t)ss[i] * MAXE + pp] =
                            make_int2(col[e + i], __float_as_int(vals[e + i]));
                }
            }
        }
    }
    __syncthreads();
    int n = cnt; n = (n < SLABCAP) ? n : SLABCAP;
    if (tid < n) hitlist[(size_t)blockIdx.x * SLABCAP + tid] = lh[tid];
    if (tid == 0) slabcnt[blockIdx.x] = n;
}

// hit processing at full parallelism: one thread per slab entry.
__global__ void __launch_bounds__(256) k_fill(
        const int* __restrict__ col,
        const float* __restrict__ vals,
        const int* __restrict__ slabcnt,
        const int2* __restrict__ hitlist,
        int* __restrict__ count,
        int2* __restrict__ csr2) {
    int idx = blockIdx.x * 256 + threadIdx.x;
    if (idx >= SLABS * SLABCAP) return;
    int s = idx >> 7;
    int i = idx & (SLABCAP - 1);
    if (i >= slabcnt[s]) return;
    int2 h = hitlist[idx];                    // (edge, slot) coalesced
    int   c = col[h.x];
    float v = vals[h.x];
    int p = atomicAdd(&count[h.y], 1);
    if (p < MAXE)
        csr2[(size_t)h.y * MAXE + p] = make_int2(c, __float_as_int(v));
}

// one wave per slot; lane-parallel edge load + shfl broadcast; 16-wide gather rounds.
__global__ void __launch_bounds__(256) k_gather(
        const int* __restrict__ users,
        const int* __restrict__ pos,
        const int* __restrict__ neg,
        const float* __restrict__ user_emb,
        const float* __restrict__ item_emb,
        const unsigned short* __restrict__ table16,
        const int* __restrict__ count,
        const int2* __restrict__ csr2,
        float* __restrict__ side) {
    int tid = threadIdx.x;
    int w = tid >> 6;
    int j = tid & 63;
    int slot = blockIdx.x * 4 + w;

    int node;
    if (slot < BATCH)          node = users[slot];
    else if (slot < 2 * BATCH) node = N_USER + pos[slot - BATCH];
    else                       node = N_USER + neg[slot - 2 * BATCH];

    int wslot = (int)(short)table16[node];        // winner slot (handles duplicates)
    wslot = __builtin_amdgcn_readfirstlane(wslot);
    int n = count[wslot];
    n = (n < MAXE) ? n : MAXE;
    n = __builtin_amdgcn_readfirstlane(n);
    const int2* base = csr2 + (size_t)wslot * MAXE;

    float acc = 0.f;
    for (int t0 = 0; t0 < n; t0 += 64) {
        int idx = t0 + j;
        int2 ev = make_int2(0, 0);
        if (idx < n) ev = base[idx];              // lane j holds edge t0+j
        int m = n - t0; m = (m < 64) ? m : 64;
        for (int tt = 0; tt < m; tt += 16) {
            float vv[16], gg[16];
            #pragma unroll
            for (int k = 0; k < 16; ++k) {
                int  t  = tt + k;
                bool okk = t < m;
                int   cc = __shfl(ev.x, t, 64);
                float vb = __uint_as_float((unsigned)__shfl(ev.y, t, 64));
                vv[k] = okk ? vb : 0.f;
                int ci = okk ? cc : 0;
                const float* sp = (ci < N_USER) ? (user_emb + (size_t)ci * EMB)
                                                : (item_emb + (size_t)(ci - N_USER) * EMB);
                gg[k] = sp[j];
            }
            #pragma unroll
            for (int k = 0; k < 16; ++k) acc = fmaf(vv[k], gg[k], acc);
        }
    }
    side[(size_t)slot * EMB + j] = acc;
}

// 4 slots per wave, 16 per block; W staged in LDS per block per layer.
__global__ void __launch_bounds__(256) k_mlp(
        const int* __restrict__ users,
        const int* __restrict__ pos,
        const int* __restrict__ neg,
        const float* __restrict__ user_emb,
        const float* __restrict__ item_emb,
        const float* __restrict__ W_gc,
        const float* __restrict__ b_gc,
        const float* __restrict__ W_bi,
        const float* __restrict__ b_bi,
        const float* __restrict__ side,
        float* __restrict__ out) {
    __shared__ float wg[EMB * EMB];
    __shared__ float wb[EMB * EMB];
    int tid = threadIdx.x;
    int w = tid >> 6;
    int j = tid & 63;
    int sbase = blockIdx.x * 16 + w * 4;

    float sval[4], e[4];
    #pragma unroll
    for (int s = 0; s < 4; ++s) {
        int slot = sbase + s;
        int node;
        if (slot < BATCH)          node = users[slot];
        else if (slot < 2 * BATCH) node = N_USER + pos[slot - BATCH];
        else                       node = N_USER + neg[slot - 2 * BATCH];
        const float* erow = (node < N_USER) ? (user_emb + (size_t)node * EMB)
                                            : (item_emb + (size_t)(node - N_USER) * EMB);
        e[s]    = erow[j];
        sval[s] = side[(size_t)slot * EMB + j];
        out[(size_t)slot * 256 + j] = e[s];       // layer-0 columns: raw ego
    }

    for (int k = 0; k < N_LAYERS; ++k) {
        __syncthreads();                          // prev-layer LDS reads done
        {
            const float4* g4 = (const float4*)(W_gc + (size_t)k * EMB * EMB);
            const float4* b4 = (const float4*)(W_bi + (size_t)k * EMB * EMB);
            float4* lg = (float4*)wg;
            float4* lb = (float4*)wb;
            #pragma unroll
            for (int i2 = tid; i2 < EMB * EMB / 4; i2 += 256) { lg[i2] = g4[i2]; lb[i2] = b4[i2]; }
        }
        __syncthreads();                          // weights ready

        float b1 = b_gc[k * EMB + j];
        float b2 = b_bi[k * EMB + j];
        float sum1[4], sum2[4], pv[4];
        #pragma unroll
        for (int s = 0; s < 4; ++s) { sum1[s] = b1; sum2[s] = b2; pv[s] = sval[s] * e[s]; }

        #pragma unroll 8
        for (int i = 0; i < EMB; ++i) {
            float wgi = wg[i * EMB + j];
            float wbi = wb[i * EMB + j];
            #pragma unroll
            for (int s = 0; s < 4; ++s) {
                float si = __uint_as_float(__builtin_amdgcn_readlane(__float_as_uint(sval[s]), i));
                float pi = __uint_as_float(__builtin_amdgcn_readlane(__float_as_uint(pv[s]),   i));
                sum1[s] = fmaf(si, wgi, sum1[s]);
                sum2[s] = fmaf(pi, wbi, sum2[s]);
            }
        }

        #pragma unroll
        for (int s = 0; s < 4; ++s) {
            float x = sum1[s] + sum2[s];
            x = (x >= 0.f) ? x : 0.2f * x;        // leaky_relu 0.2
            float sq = x * x;                     // wave-wide L2 norm
            #pragma unroll
            for (int o = 32; o; o >>= 1) sq += __shfl_xor(sq, o, 64);
            float nn = fmaxf(sqrtf(sq), 1e-12f);
            out[(size_t)(sbase + s) * 256 + (k + 1) * 64 + j] = x / nn;
            e[s] = x;                             // next-layer ego = unnormalized output
        }
    }
}

extern "C" void kernel_launch(void* const* d_in, const int* in_sizes, int n_in,
                              void* d_out, int out_size, void* d_ws, size_t ws_size,
                              hipStream_t stream) {
    const int*   users    = (const int*)  d_in[0];
    const int*   pos      = (const int*)  d_in[1];
    const int*   neg      = (const int*)  d_in[2];
    const int*   row      = (const int*)  d_in[3];
    const int*   col      = (const int*)  d_in[4];
    const float* vals     = (const float*)d_in[5];
    const float* user_emb = (const float*)d_in[6];
    const float* item_emb = (const float*)d_in[7];
    const float* W_gc     = (const float*)d_in[8];
    const float* b_gc     = (const float*)d_in[9];
    const float* W_bi     = (const float*)d_in[10];
    const float* b_bi     = (const float*)d_in[11];
    float* out = (float*)d_out;

    char* ws = (char*)d_ws;
    unsigned short* table16 = (unsigned short*)ws;
    int*            count   = (int*)(ws + 600064);
    int2*           csr2    = (int2*)(ws + 649216);
    float*          side    = (float*)(ws + 10086400);
    int*            slabcnt = (int*)(ws + 13232128);
    int2*           hitlist = (int2*)(ws + 13248512);

    k_clear<<<(TBL4 + CNT4 + SCNT4 + 255) / 256, 256, 0, stream>>>(
        (int4*)table16, (int4*)count, (int4*)slabcnt);
    k_setup<<<(NSLOT + 255) / 256, 256, 0, stream>>>(users, pos, neg, table16);
    k_scan<<<SLABS, 256, 0, stream>>>(row, table16, col, vals, count, csr2,
                                      slabcnt, hitlist);
    k_fill<<<(SLABS * SLABCAP + 255) / 256, 256, 0, stream>>>(
        col, vals, slabcnt, hitlist, count, csr2);
    k_gather<<<NSLOT / 4, 256, 0, stream>>>(users, pos, neg, user_emb, item_emb,
                                            table16, count, csr2, side);
    k_mlp<<<NSLOT / 16, 256, 0, stream>>>(users, pos, neg, user_emb, item_emb,
                                          W_gc, b_gc, W_bi, b_bi, side, out);
}

// Round 11
// 76.791 us; speedup vs baseline: 1.1632x; 1.1632x over previous
//
#include <hip/hip_runtime.h>

#define N_USER   100000
#define N_ITEM   200000
#define N_NODES  300000
#define NNZ      4000000
#define EMB      64
#define N_LAYERS 3
#define BATCH    4096
#define NSLOT    (3*BATCH)   // 12288
#define MAXE     96          // bucket capacity; edges/node ~ Poisson(13.3)
#define HCAP     256         // hits per 1024-edge block ~ N(42,6.5) -> 33 sigma
#define BMWORDS  9376        // ceil(300000/32)

// ---------------- ws layout ----------------
// [0]         u16  table16[N_NODES]       600,000 B (pad 600,064)  -- NEVER cleared (bitmap-gated)
// [600064]    int  count[NSLOT]           49,152 B
// [649216]    int2 csr2[NSLOT*MAXE]       9,437,184 B  (col, val-bits)
// [10086400]  float side[NSLOT*EMB]       3,145,728 B
// [13232128]  uint bitmap[BMWORDS]        37,504 B (pad 37,632)

#define CNT4   3072      // 49,152/16
#define BM4    2344      // 37,504/16

// clear only count + bitmap (86 KB total; table16 stays garbage behind the bitmap gate)
__global__ void __launch_bounds__(256) k_clear(int4* __restrict__ c4,
                                               int4* __restrict__ b4) {
    int i = blockIdx.x * blockDim.x + threadIdx.x;
    if (i < CNT4)            c4[i] = make_int4(0, 0, 0, 0);
    else if (i < CNT4 + BM4) b4[i - CNT4] = make_int4(0, 0, 0, 0);
}

__global__ void k_setup(const int* __restrict__ users,
                        const int* __restrict__ pos,
                        const int* __restrict__ neg,
                        unsigned short* __restrict__ table16,
                        unsigned int* __restrict__ bitmap) {
    int i = blockIdx.x * blockDim.x + threadIdx.x;
    if (i >= NSLOT) return;
    int node;
    if (i < BATCH)            node = users[i];
    else if (i < 2 * BATCH)   node = N_USER + pos[i - BATCH];
    else                      node = N_USER + neg[i - 2 * BATCH];
    table16[node] = (unsigned short)i;        // benign race on duplicates (winner consistent)
    atomicOr(&bitmap[((unsigned)node) >> 5], 1u << (node & 31));
}

// merged build: stream row+col+vals coalesced; membership via 37.5 KB bitmap
// (L1/L2-hot) so only ~4.3% of lanes pay the table16 L2 gather; LDS-compact
// hits; phase B wave-dense: one count atomic + one int2 store per hit.
__global__ void __launch_bounds__(256) k_build(
        const int* __restrict__ row,
        const int* __restrict__ col,
        const float* __restrict__ vals,
        const unsigned int* __restrict__ bitmap,
        const unsigned short* __restrict__ table16,
        int* __restrict__ count,
        int2* __restrict__ csr2) {
    __shared__ int   ls_s[HCAP];
    __shared__ int   ls_c[HCAP];
    __shared__ float ls_v[HCAP];
    __shared__ int   cnt;
    int tid = threadIdx.x;
    if (tid == 0) cnt = 0;
    __syncthreads();

    int t = blockIdx.x * 256 + tid;           // int4-tile index (4 edges)
    if (t < NNZ / 4) {
        int4   r = ((const int4*)row)[t];
        int4   c = ((const int4*)col)[t];
        float4 v = ((const float4*)vals)[t];
        // bitmap tests (hot in L1/L2) — gathers but tiny working set
        bool h0 = (bitmap[((unsigned)r.x) >> 5] >> (r.x & 31)) & 1;
        bool h1 = (bitmap[((unsigned)r.y) >> 5] >> (r.y & 31)) & 1;
        bool h2 = (bitmap[((unsigned)r.z) >> 5] >> (r.z & 31)) & 1;
        bool h3 = (bitmap[((unsigned)r.w) >> 5] >> (r.w & 31)) & 1;
        int rr[4] = { r.x, r.y, r.z, r.w };
        int cc[4] = { c.x, c.y, c.z, c.w };
        float vv[4] = { v.x, v.y, v.z, v.w };
        bool hh[4] = { h0, h1, h2, h3 };
        #pragma unroll
        for (int i = 0; i < 4; ++i) {
            if (hh[i]) {
                int si = (int)table16[rr[i]]; // only hits touch the 600 KB table
                int p = atomicAdd(&cnt, 1);   // LDS atomic (wave-aggregated)
                if (p < HCAP) { ls_s[p] = si; ls_c[p] = cc[i]; ls_v[p] = vv[i]; }
                else {                        // statistically never (33 sigma)
                    int pp = atomicAdd(&count[si], 1);
                    if (pp < MAXE)
                        csr2[(size_t)si * MAXE + pp] = make_int2(cc[i], __float_as_int(vv[i]));
                }
            }
        }
    }
    __syncthreads();

    int n = cnt; n = (n < HCAP) ? n : HCAP;
    for (int t2 = tid; t2 < n; t2 += 256) {
        int si = ls_s[t2];
        int p = atomicAdd(&count[si], 1);
        if (p < MAXE)
            csr2[(size_t)si * MAXE + p] = make_int2(ls_c[t2], __float_as_int(ls_v[t2]));
    }
}

// one wave per slot; lane-parallel edge load + shfl broadcast; 16-wide gather rounds.
__global__ void __launch_bounds__(256) k_gather(
        const int* __restrict__ users,
        const int* __restrict__ pos,
        const int* __restrict__ neg,
        const float* __restrict__ user_emb,
        const float* __restrict__ item_emb,
        const unsigned short* __restrict__ table16,
        const int* __restrict__ count,
        const int2* __restrict__ csr2,
        float* __restrict__ side) {
    int tid = threadIdx.x;
    int w = tid >> 6;
    int j = tid & 63;
    int slot = blockIdx.x * 4 + w;

    int node;
    if (slot < BATCH)          node = users[slot];
    else if (slot < 2 * BATCH) node = N_USER + pos[slot - BATCH];
    else                       node = N_USER + neg[slot - 2 * BATCH];

    int wslot = (int)table16[node];               // winner slot (always marked)
    wslot = __builtin_amdgcn_readfirstlane(wslot);
    int n = count[wslot];
    n = (n < MAXE) ? n : MAXE;
    n = __builtin_amdgcn_readfirstlane(n);
    const int2* base = csr2 + (size_t)wslot * MAXE;

    float acc = 0.f;
    for (int t0 = 0; t0 < n; t0 += 64) {
        int idx = t0 + j;
        int2 ev = make_int2(0, 0);
        if (idx < n) ev = base[idx];              // lane j holds edge t0+j
        int m = n - t0; m = (m < 64) ? m : 64;
        for (int tt = 0; tt < m; tt += 16) {
            float vv[16], gg[16];
            #pragma unroll
            for (int k = 0; k < 16; ++k) {
                int  t  = tt + k;
                bool okk = t < m;
                int   cc = __shfl(ev.x, t, 64);
                float vb = __uint_as_float((unsigned)__shfl(ev.y, t, 64));
                vv[k] = okk ? vb : 0.f;
                int ci = okk ? cc : 0;
                const float* sp = (ci < N_USER) ? (user_emb + (size_t)ci * EMB)
                                                : (item_emb + (size_t)(ci - N_USER) * EMB);
                gg[k] = sp[j];
            }
            #pragma unroll
            for (int k = 0; k < 16; ++k) acc = fmaf(vv[k], gg[k], acc);
        }
    }
    side[(size_t)slot * EMB + j] = acc;
}

// 4 slots per wave, 16 per block; W staged in LDS per block per layer.
__global__ void __launch_bounds__(256) k_mlp(
        const int* __restrict__ users,
        const int* __restrict__ pos,
        const int* __restrict__ neg,
        const float* __restrict__ user_emb,
        const float* __restrict__ item_emb,
        const float* __restrict__ W_gc,
        const float* __restrict__ b_gc,
        const float* __restrict__ W_bi,
        const float* __restrict__ b_bi,
        const float* __restrict__ side,
        float* __restrict__ out) {
    __shared__ float wg[EMB * EMB];
    __shared__ float wb[EMB * EMB];
    int tid = threadIdx.x;
    int w = tid >> 6;
    int j = tid & 63;
    int sbase = blockIdx.x * 16 + w * 4;

    float sval[4], e[4];
    #pragma unroll
    for (int s = 0; s < 4; ++s) {
        int slot = sbase + s;
        int node;
        if (slot < BATCH)          node = users[slot];
        else if (slot < 2 * BATCH) node = N_USER + pos[slot - BATCH];
        else                       node = N_USER + neg[slot - 2 * BATCH];
        const float* erow = (node < N_USER) ? (user_emb + (size_t)node * EMB)
                                            : (item_emb + (size_t)(node - N_USER) * EMB);
        e[s]    = erow[j];
        sval[s] = side[(size_t)slot * EMB + j];
        out[(size_t)slot * 256 + j] = e[s];       // layer-0 columns: raw ego
    }

    for (int k = 0; k < N_LAYERS; ++k) {
        __syncthreads();                          // prev-layer LDS reads done
        {
            const float4* g4 = (const float4*)(W_gc + (size_t)k * EMB * EMB);
            const float4* b4 = (const float4*)(W_bi + (size_t)k * EMB * EMB);
            float4* lg = (float4*)wg;
            float4* lb = (float4*)wb;
            #pragma unroll
            for (int i2 = tid; i2 < EMB * EMB / 4; i2 += 256) { lg[i2] = g4[i2]; lb[i2] = b4[i2]; }
        }
        __syncthreads();                          // weights ready

        float b1 = b_gc[k * EMB + j];
        float b2 = b_bi[k * EMB + j];
        float sum1[4], sum2[4], pv[4];
        #pragma unroll
        for (int s = 0; s < 4; ++s) { sum1[s] = b1; sum2[s] = b2; pv[s] = sval[s] * e[s]; }

        #pragma unroll 8
        for (int i = 0; i < EMB; ++i) {
            float wgi = wg[i * EMB + j];
            float wbi = wb[i * EMB + j];
            #pragma unroll
            for (int s = 0; s < 4; ++s) {
                float si = __uint_as_float(__builtin_amdgcn_readlane(__float_as_uint(sval[s]), i));
                float pi = __uint_as_float(__builtin_amdgcn_readlane(__float_as_uint(pv[s]),   i));
                sum1[s] = fmaf(si, wgi, sum1[s]);
                sum2[s] = fmaf(pi, wbi, sum2[s]);
            }
        }

        #pragma unroll
        for (int s = 0; s < 4; ++s) {
            float x = sum1[s] + sum2[s];
            x = (x >= 0.f) ? x : 0.2f * x;        // leaky_relu 0.2
            float sq = x * x;                     // wave-wide L2 norm
            #pragma unroll
            for (int o = 32; o; o >>= 1) sq += __shfl_xor(sq, o, 64);
            float nn = fmaxf(sqrtf(sq), 1e-12f);
            out[(size_t)(sbase + s) * 256 + (k + 1) * 64 + j] = x / nn;
            e[s] = x;                             // next-layer ego = unnormalized output
        }
    }
}

extern "C" void kernel_launch(void* const* d_in, const int* in_sizes, int n_in,
                              void* d_out, int out_size, void* d_ws, size_t ws_size,
                              hipStream_t stream) {
    const int*   users    = (const int*)  d_in[0];
    const int*   pos      = (const int*)  d_in[1];
    const int*   neg      = (const int*)  d_in[2];
    const int*   row      = (const int*)  d_in[3];
    const int*   col      = (const int*)  d_in[4];
    const float* vals     = (const float*)d_in[5];
    const float* user_emb = (const float*)d_in[6];
    const float* item_emb = (const float*)d_in[7];
    const float* W_gc     = (const float*)d_in[8];
    const float* b_gc     = (const float*)d_in[9];
    const float* W_bi     = (const float*)d_in[10];
    const float* b_bi     = (const float*)d_in[11];
    float* out = (float*)d_out;

    char* ws = (char*)d_ws;
    unsigned short* table16 = (unsigned short*)ws;
    int*            count   = (int*)(ws + 600064);
    int2*           csr2    = (int2*)(ws + 649216);
    float*          side    = (float*)(ws + 10086400);
    unsigned int*   bitmap  = (unsigned int*)(ws + 13232128);

    k_clear<<<(CNT4 + BM4 + 255) / 256, 256, 0, stream>>>((int4*)count, (int4*)bitmap);
    k_setup<<<(NSLOT + 255) / 256, 256, 0, stream>>>(users, pos, neg, table16, bitmap);
    k_build<<<(NNZ / 4 + 255) / 256, 256, 0, stream>>>(row, col, vals, bitmap,
                                                       table16, count, csr2);
    k_gather<<<NSLOT / 4, 256, 0, stream>>>(users, pos, neg, user_emb, item_emb,
                                            table16, count, csr2, side);
    k_mlp<<<NSLOT / 16, 256, 0, stream>>>(users, pos, neg, user_emb, item_emb,
                                          W_gc, b_gc, W_bi, b_bi, side, out);
}